// Round 12
// baseline (417.040 us; speedup 1.0000x reference)
//
#include <hip/hip_runtime.h>
#include <hip/hip_bf16.h>
#include <stdint.h>
#include <stddef.h>

typedef __bf16 bf16;
typedef __attribute__((ext_vector_type(8))) __bf16 bf16x8;
typedef __attribute__((ext_vector_type(4))) __bf16 bf16x4;
typedef __attribute__((ext_vector_type(4))) float f32x4;

#define DM 2048      // model dim
#define NH 16        // heads
#define HDD 128      // head dim
#define BB 2         // batch
#define TT 2048      // seq len
#define MM (BB*TT)   // 4096 rows
#define NQKV (3*DM)  // 6144

#define L2E 1.4426950408889634f
#define ATT_SCALE 0.08838834764831845f   // 1/sqrt(128), folded into Q at RoPE
#define NEG_INF (-__builtin_inff())

static_assert(sizeof(bf16x8) == 16, "bf16x8 must be 16B");

#define SB0() __builtin_amdgcn_sched_barrier(0)
#define WAITV0() { asm volatile("s_waitcnt vmcnt(0)" ::: "memory"); SB0(); }
#define WAITL0() { asm volatile("s_waitcnt lgkmcnt(0)" ::: "memory"); SB0(); }
#define BARRIER8() { SB0(); __builtin_amdgcn_s_barrier(); SB0(); }

// ---------------------------------------------------------------- helpers
static __device__ __forceinline__ void gload_lds16(const void* g, void* l) {
  __builtin_amdgcn_global_load_lds(
      (__attribute__((address_space(1))) void*)g,
      (__attribute__((address_space(3))) void*)l, 16, 0, 0);
}

// ---------------------------------------------------------------- pre-pass
__global__ __launch_bounds__(256) void rope_table_k(float* __restrict__ cT,
                                                    float* __restrict__ sT) {
  int id = blockIdx.x * 256 + threadIdx.x;          // < 2048*64
  int t = id >> 6, i = id & 63;
  float freq = powf(10000.0f, -(float)i * (1.0f / 64.0f));
  float theta = (float)t * freq;
  float s, c;
  __sincosf(theta, &s, &c);
  cT[id] = c;
  sT[id] = s;
}

__global__ __launch_bounds__(256) void convert_x_k(const float* __restrict__ x,
                                                   bf16* __restrict__ xb) {
  size_t id = (size_t)blockIdx.x * 256 + threadIdx.x;
  size_t o = id * 8;
  float4 a = *(const float4*)(x + o);
  float4 b = *(const float4*)(x + o + 4);
  bf16x8 r;
  r[0] = (bf16)a.x; r[1] = (bf16)a.y; r[2] = (bf16)a.z; r[3] = (bf16)a.w;
  r[4] = (bf16)b.x; r[5] = (bf16)b.y; r[6] = (bf16)b.z; r[7] = (bf16)b.w;
  *(bf16x8*)(xb + o) = r;
}

// W (K x N) f32 -> Wt (N x K) bf16, 64x64 tiles
__global__ __launch_bounds__(256) void transpose_w_k(const float* __restrict__ W,
                                                     bf16* __restrict__ Wt,
                                                     int K, int N) {
  __shared__ float tile[64][65];
  int n0 = blockIdx.x * 64, k0 = blockIdx.y * 64;
  int t = threadIdx.x;
#pragma unroll
  for (int i = 0; i < 16; ++i) {
    int idx = t + i * 256;
    int r = idx >> 6, c = idx & 63;
    tile[r][c] = W[(size_t)(k0 + r) * N + n0 + c];
  }
  __syncthreads();
#pragma unroll
  for (int i = 0; i < 16; ++i) {
    int idx = t + i * 256;
    int r = idx >> 6, c = idx & 63;
    Wt[(size_t)(n0 + r) * K + k0 + c] = (bf16)tile[c][r];
  }
}

// in-place RoPE on (b,h,t,hd) bf16 buffer; SC folds ATT_SCALE (for Q)
template <bool SC>
__global__ __launch_bounds__(256) void rope_apply_k(bf16* __restrict__ buf,
                                                    const float* __restrict__ cT,
                                                    const float* __restrict__ sT) {
  int id = blockIdx.x * 256 + threadIdx.x;   // < 32*2048*16
  int i4 = id & 15;
  int t = (id >> 4) & 2047;
  int bh = id >> 15;
  int idx0 = i4 * 4;
  size_t base = ((size_t)bh * TT + t) * HDD;
  bf16x4 x1 = *(const bf16x4*)(buf + base + idx0);
  bf16x4 x2 = *(const bf16x4*)(buf + base + 64 + idx0);
  float4 ct = *(const float4*)(cT + t * 64 + idx0);
  float4 st = *(const float4*)(sT + t * 64 + idx0);
  bf16x4 o1, o2;
  float c0, s0, a, b2;
  const float scl = SC ? ATT_SCALE : 1.0f;
#pragma unroll
  for (int j = 0; j < 4; ++j) {
    c0 = (j == 0) ? ct.x : (j == 1) ? ct.y : (j == 2) ? ct.z : ct.w;
    s0 = (j == 0) ? st.x : (j == 1) ? st.y : (j == 2) ? st.z : st.w;
    a = (float)x1[j];
    b2 = (float)x2[j];
    o1[j] = (bf16)((a * c0 - b2 * s0) * scl);
    o2[j] = (bf16)((a * s0 + b2 * c0) * scl);
  }
  *(bf16x4*)(buf + base + idx0) = o1;
  *(bf16x4*)(buf + base + 64 + idx0) = o2;
}

// ---------------------------------------------------------------- GEMM (QKV, 4-phase 256x192)
#define MFMA_Q(MF0, NF0, NCNT)                                             \
  do {                                                                     \
    __builtin_amdgcn_s_setprio(1);                                         \
    _Pragma("unroll") for (int mf = 0; mf < 4; ++mf)                       \
    _Pragma("unroll") for (int nf = 0; nf < (NCNT); ++nf)                  \
    _Pragma("unroll") for (int kk = 0; kk < 2; ++kk)                       \
      acc[(MF0) + mf][(NF0) + nf] = __builtin_amdgcn_mfma_f32_16x16x32_bf16( \
          af[(MF0) + mf][kk], bfr[(NF0) + nf][kk], acc[(MF0) + mf][(NF0) + nf], 0, 0, 0); \
    __builtin_amdgcn_s_setprio(0);                                         \
  } while (0)

__global__ __launch_bounds__(512, 2) void gemm8_qkv_k(
    const bf16* __restrict__ A, const bf16* __restrict__ Bt,
    const float* __restrict__ bias,
    bf16* __restrict__ q_out, bf16* __restrict__ k_out, bf16* __restrict__ v_out,
    int M, int N, int K) {
  __shared__ __align__(16) char Lsm[2][57344];   // [buf][A:32KB | B:24KB]
  const int tid = threadIdx.x;
  const int wid = tid >> 6, l = tid & 63;
  const int lane16 = l & 15, lgrp = l >> 4;
  const int wm = wid >> 2, wn = wid & 3;

  int flat = blockIdx.y * gridDim.x + blockIdx.x;
  {
    const int cpx = (gridDim.x * gridDim.y) >> 3;
    flat = (flat & 7) * cpx + (flat >> 3);
  }
  const int bm = flat % gridDim.x;       // 0..15  (M/256)
  const int bn = flat / gridDim.x;       // 0..31  (N/192)
  const int NT = K >> 6;

  const int schunk = (l & 7) ^ ((l >> 3) & 7);
  const bf16* gA = A + (size_t)(bm * 256 + wid * 8 + (l >> 3)) * K + schunk * 8;
  const bf16* gB = Bt + (size_t)(bn * 192 + wid * 8 + (l >> 3)) * K + schunk * 8;

  auto stage_unit = [&](int mat, int t, int u, int buf) {
    const bf16* g = (mat ? gB : gA) + (size_t)(u * 64) * K + t * 64;
    gload_lds16(g, &Lsm[buf][(mat ? 32768 : 0) + u * 8192 + wid * 1024]);
  };

  f32x4 acc[8][3] = {};

#pragma unroll
  for (int u = 0; u < 4; ++u) stage_unit(0, 0, u, 0);
#pragma unroll
  for (int u = 0; u < 3; ++u) stage_unit(1, 0, u, 0);

  for (int t = 0; t < NT; ++t) {
    const int cur = t & 1;
    const char* As = &Lsm[cur][0];
    const char* Bs = &Lsm[cur][32768];
    bf16x8 af[8][2], bfr[3][2];

    WAITV0();
    BARRIER8();

    // ---- phase 0
#pragma unroll
    for (int mf = 0; mf < 4; ++mf)
#pragma unroll
      for (int kk = 0; kk < 2; ++kk) {
        int row = wm * 128 + mf * 16 + lane16;
        int ch = (kk * 4 + lgrp) ^ (lane16 & 7);
        af[mf][kk] = *(const bf16x8*)(As + row * 128 + ch * 16);
      }
#pragma unroll
    for (int nf = 0; nf < 2; ++nf)
#pragma unroll
      for (int kk = 0; kk < 2; ++kk) {
        int row = wn * 48 + nf * 16 + lane16;
        int ch = (kk * 4 + lgrp) ^ (lane16 & 7);
        bfr[nf][kk] = *(const bf16x8*)(Bs + row * 128 + ch * 16);
      }
    if (t + 1 < NT) {
#pragma unroll
      for (int u = 0; u < 4; ++u) stage_unit(0, t + 1, u, cur ^ 1);
    }
    WAITL0();
    MFMA_Q(0, 0, 2);
    BARRIER8();

    // ---- phase 1
#pragma unroll
    for (int mf = 4; mf < 8; ++mf)
#pragma unroll
      for (int kk = 0; kk < 2; ++kk) {
        int row = wm * 128 + mf * 16 + lane16;
        int ch = (kk * 4 + lgrp) ^ (lane16 & 7);
        af[mf][kk] = *(const bf16x8*)(As + row * 128 + ch * 16);
      }
#pragma unroll
    for (int kk = 0; kk < 2; ++kk) {
      int row = wn * 48 + 32 + lane16;
      int ch = (kk * 4 + lgrp) ^ (lane16 & 7);
      bfr[2][kk] = *(const bf16x8*)(Bs + row * 128 + ch * 16);
    }
    if (t + 1 < NT) {
#pragma unroll
      for (int u = 0; u < 3; ++u) stage_unit(1, t + 1, u, cur ^ 1);
    }
    WAITL0();
    MFMA_Q(0, 2, 1);
    BARRIER8();

    // ---- phase 2
    MFMA_Q(4, 0, 2);
    BARRIER8();

    // ---- phase 3
    MFMA_Q(4, 2, 1);
  }

  // ---- epilogue
#pragma unroll
  for (int nf = 0; nf < 3; ++nf) {
    int colg = bn * 192 + wn * 48 + nf * 16 + lane16;
    int which = colg >> 11;
    bf16* outb = (which == 0) ? q_out : (which == 1 ? k_out : v_out);
    int head = (colg >> 7) & 15, hd = colg & 127;
    float bv = bias[colg];
#pragma unroll
    for (int mf = 0; mf < 8; ++mf)
#pragma unroll
      for (int r = 0; r < 4; ++r) {
        int row = bm * 256 + wm * 128 + mf * 16 + lgrp * 4 + r;
        int bb = row >> 11, tt2 = row & 2047;
        outb[((size_t)(bb * NH + head) * TT + tt2) * HDD + hd] =
            (bf16)(acc[mf][nf][r] + bv);
      }
  }
}

// ---------------------------------------------------------------- GEMM (proj, 4-phase 256x128)
__global__ __launch_bounds__(512, 2) void gemm4_proj_k(
    const bf16* __restrict__ A, const bf16* __restrict__ Bt,
    const float* __restrict__ bias, float* __restrict__ c_out,
    int M, int N, int K) {
  __shared__ __align__(16) char Lsm[2][49152];   // [buf][A:32KB | B:16KB]
  const int tid = threadIdx.x;
  const int wid = tid >> 6, l = tid & 63;
  const int lane16 = l & 15, lgrp = l >> 4;
  const int wm = wid >> 2, wn = wid & 3;

  int flat = blockIdx.y * gridDim.x + blockIdx.x;
  {
    const int cpx = (gridDim.x * gridDim.y) >> 3;
    flat = (flat & 7) * cpx + (flat >> 3);
  }
  const int bm = flat % gridDim.x;       // 0..15 (M/256)
  const int bn = flat / gridDim.x;       // 0..15 (N/128)
  const int NT = K >> 6;

  const int schunk = (l & 7) ^ ((l >> 3) & 7);
  const bf16* gA = A + (size_t)(bm * 256 + wid * 8 + (l >> 3)) * K + schunk * 8;
  const bf16* gB = Bt + (size_t)(bn * 128 + wid * 8 + (l >> 3)) * K + schunk * 8;

  auto stage_unit = [&](int mat, int t, int u, int buf) {
    const bf16* g = (mat ? gB : gA) + (size_t)(u * 64) * K + t * 64;
    gload_lds16(g, &Lsm[buf][(mat ? 32768 : 0) + u * 8192 + wid * 1024]);
  };

  f32x4 acc[8][2] = {};

#pragma unroll
  for (int u = 0; u < 4; ++u) stage_unit(0, 0, u, 0);
#pragma unroll
  for (int u = 0; u < 2; ++u) stage_unit(1, 0, u, 0);

  for (int t = 0; t < NT; ++t) {
    const int cur = t & 1;
    const char* As = &Lsm[cur][0];
    const char* Bs = &Lsm[cur][32768];
    bf16x8 af[8][2], bfr[2][2];

    WAITV0();
    BARRIER8();

    // ---- phase 0
#pragma unroll
    for (int mf = 0; mf < 4; ++mf)
#pragma unroll
      for (int kk = 0; kk < 2; ++kk) {
        int row = wm * 128 + mf * 16 + lane16;
        int ch = (kk * 4 + lgrp) ^ (lane16 & 7);
        af[mf][kk] = *(const bf16x8*)(As + row * 128 + ch * 16);
      }
#pragma unroll
    for (int nf = 0; nf < 2; ++nf)
#pragma unroll
      for (int kk = 0; kk < 2; ++kk) {
        int row = wn * 32 + nf * 16 + lane16;
        int ch = (kk * 4 + lgrp) ^ (lane16 & 7);
        bfr[nf][kk] = *(const bf16x8*)(Bs + row * 128 + ch * 16);
      }
    if (t + 1 < NT) {
#pragma unroll
      for (int u = 0; u < 4; ++u) stage_unit(0, t + 1, u, cur ^ 1);
    }
    WAITL0();
    MFMA_Q(0, 0, 1);
    BARRIER8();

    // ---- phase 1
#pragma unroll
    for (int mf = 4; mf < 8; ++mf)
#pragma unroll
      for (int kk = 0; kk < 2; ++kk) {
        int row = wm * 128 + mf * 16 + lane16;
        int ch = (kk * 4 + lgrp) ^ (lane16 & 7);
        af[mf][kk] = *(const bf16x8*)(As + row * 128 + ch * 16);
      }
    if (t + 1 < NT) {
#pragma unroll
      for (int u = 0; u < 2; ++u) stage_unit(1, t + 1, u, cur ^ 1);
    }
    WAITL0();
    MFMA_Q(0, 1, 1);
    BARRIER8();

    // ---- phase 2
    MFMA_Q(4, 0, 1);
    BARRIER8();

    // ---- phase 3
    MFMA_Q(4, 1, 1);
  }

  // ---- epilogue: bias + f32 row-major store
#pragma unroll
  for (int nf = 0; nf < 2; ++nf) {
    int colg = bn * 128 + wn * 32 + nf * 16 + lane16;
    float bv = bias[colg];
#pragma unroll
    for (int mf = 0; mf < 8; ++mf)
#pragma unroll
      for (int r = 0; r < 4; ++r) {
        int row = bm * 256 + wm * 128 + mf * 16 + lgrp * 4 + r;
        c_out[(size_t)row * N + colg] = acc[mf][nf][r] + bv;
      }
  }
}

// ---------------------------------------------------------------- attention
// R9-proven structure. R12 changes (arithmetic only): ATT_SCALE pre-folded
// into Q (mask loop only on diagonal tile); defer-max THR=8 (skip O-rescale
// when tile max within 8 nats of running max; P bounded by e^8, bf16-safe).
__global__ __launch_bounds__(512, 2) void attn_k(
    const bf16* __restrict__ Q, const bf16* __restrict__ Kt,
    const bf16* __restrict__ V, bf16* __restrict__ Y) {
  __shared__ __align__(16) bf16 Ksm[128 * 128];   // [key][hd], chunk^=g4(key), 32KB
  __shared__ __align__(16) bf16 Vsm[128 * 128];   // [hd][key], chunk^=g4(hd), 32KB
  __shared__ __align__(16) bf16 Psm[8][16 * 128]; // per-wave P, chunk^=g4(row), 32KB
  const int tid = threadIdx.x, w = tid >> 6, l = tid & 63;
  const int lane16 = l & 15, lgrp = l >> 4;
  const int bh = blockIdx.y;
  const int b = bh >> 4, h = bh & 15;
  const size_t base = (size_t)bh * TT * HDD;

  uint4 vreg[4];
  const int vg = tid >> 4, vh8 = tid & 15;

  auto load_V = [&](int k0) {
#pragma unroll
    for (int kq = 0; kq < 4; ++kq)
      vreg[kq] = *(const uint4*)(V + base + (size_t)(k0 + vg * 4 + kq) * HDD + vh8 * 8);
  };
  auto issue_K = [&](int k0) {
#pragma unroll
    for (int i = 0; i < 4; ++i) {
      int key = w * 16 + i * 4 + (l >> 4);
      int c = (l & 15) ^ ((key ^ (key >> 3)) & 15);
      gload_lds16(Kt + base + (size_t)(k0 + key) * HDD + c * 8,
                  &Ksm[(w * 16 + i * 4) * 128 + (l & 15) * 8]);
    }
  };
  auto write_V = [&]() {
    const unsigned* dw = (const unsigned*)vreg;
    int hd0 = vh8 * 8;
#pragma unroll
    for (int j = 0; j < 8; ++j) {
      int ww = j >> 1;
      unsigned sel = (j & 1) ? 0x07060302u : 0x05040100u;
      uint2 val;
      val.x = __builtin_amdgcn_perm(dw[4 + ww], dw[0 + ww], sel);
      val.y = __builtin_amdgcn_perm(dw[12 + ww], dw[8 + ww], sel);
      int hd = hd0 + j;
      int ch = (vg >> 1) ^ ((hd ^ (hd >> 3)) & 15);
      *(uint2*)((char*)Vsm + hd * 256 + (ch << 4) + ((vg & 1) << 3)) = val;
    }
  };

  for (int pass = 0; pass < 2; ++pass) {
    const int qt = (pass == 0) ? (int)blockIdx.x : 15 - (int)blockIdx.x;
    const int q0 = qt * 128;
    const int nt = qt + 1;

    bf16x8 qa[4];
    {
      int row = q0 + w * 16 + lane16;
#pragma unroll
      for (int kk = 0; kk < 4; ++kk)
        qa[kk] = *(const bf16x8*)(Q + base + (size_t)row * HDD + kk * 32 + lgrp * 8);
    }

    f32x4 o[8] = {};
    float m_r[4], l_r[4];
#pragma unroll
    for (int r = 0; r < 4; ++r) { m_r[r] = NEG_INF; l_r[r] = 0.f; }

    for (int kt = 0; kt < nt; ++kt) {
      const int k0 = kt * 128;
      load_V(k0);           // V loads first (oldest in vmcnt queue)
      issue_K(k0);          // K direct-to-LDS, in flight during V repack
      write_V();            // waits only the 4 V loads; WAR safe (prev barrier)
      __syncthreads();      // drains vmcnt+lgkmcnt: K & V staged for all waves

      // ---- S = Q K^T  (logits pre-scaled via Q)
      f32x4 s[8] = {};
#pragma unroll
      for (int kk = 0; kk < 4; ++kk) {
#pragma unroll
        for (int nf = 0; nf < 8; ++nf) {
          int key = nf * 16 + lane16;
          int ch = (kk * 4 + lgrp) ^ ((key ^ (key >> 3)) & 15);
          bf16x8 kf = *(const bf16x8*)((char*)Ksm + key * 256 + (ch << 4));
          s[nf] = __builtin_amdgcn_mfma_f32_16x16x32_bf16(
              qa[kk], kf, s[nf], 0, 0, 0);
        }
      }

      // ---- causal mask (diagonal tile only)
      if (k0 + 127 > q0 + w * 16) {
        const int rowbase = q0 + w * 16 + lgrp * 4;
#pragma unroll
        for (int nf = 0; nf < 8; ++nf) {
          int col = k0 + nf * 16 + lane16;
#pragma unroll
          for (int r = 0; r < 4; ++r)
            if (col > rowbase + r) s[nf][r] = -3.0e38f;
        }
      }

      // ---- online softmax with defer-max (THR=8 nats; P <= e^8)
#pragma unroll
      for (int r = 0; r < 4; ++r) {
        float tm = fmaxf(fmaxf(fmaxf(s[0][r], s[1][r]), fmaxf(s[2][r], s[3][r])),
                         fmaxf(fmaxf(s[4][r], s[5][r]), fmaxf(s[6][r], s[7][r])));
        tm = fmaxf(tm, __shfl_xor(tm, 1));
        tm = fmaxf(tm, __shfl_xor(tm, 2));
        tm = fmaxf(tm, __shfl_xor(tm, 4));
        tm = fmaxf(tm, __shfl_xor(tm, 8));
        float mo = m_r[r];
        if (tm > mo + 8.0f) {
          float al = exp2f((mo - tm) * L2E);
          m_r[r] = tm;
          l_r[r] *= al;
#pragma unroll
          for (int nf = 0; nf < 8; ++nf) o[nf][r] *= al;
        }
        float mm = m_r[r];
        float rs = 0.f;
#pragma unroll
        for (int nf = 0; nf < 8; ++nf) {
          float p = exp2f((s[nf][r] - mm) * L2E);
          s[nf][r] = p;
          rs += p;
        }
        rs += __shfl_xor(rs, 1);
        rs += __shfl_xor(rs, 2);
        rs += __shfl_xor(rs, 4);
        rs += __shfl_xor(rs, 8);
        l_r[r] += rs;
      }

      // ---- P -> LDS (per-wave region, same-wave readback; no barrier)
#pragma unroll
      for (int nf = 0; nf < 8; ++nf)
#pragma unroll
        for (int r = 0; r < 4; ++r) {
          int rl = lgrp * 4 + r;
          int ch = (2 * nf + (lane16 >> 3)) ^ ((rl ^ (rl >> 3)) & 15);
          int byte = rl * 256 + (ch << 4) + ((lane16 & 7) << 1);
          *(bf16*)((char*)&Psm[w][0] + byte) = (bf16)s[nf][r];
        }
      bf16x8 pa[4];
#pragma unroll
      for (int kk = 0; kk < 4; ++kk) {
        int ch = (kk * 4 + lgrp) ^ ((lane16 ^ (lane16 >> 3)) & 15);
        pa[kk] = *(const bf16x8*)((char*)&Psm[w][0] + lane16 * 256 + (ch << 4));
      }

      // ---- O += P V
#pragma unroll
      for (int nf = 0; nf < 8; ++nf) {
#pragma unroll
        for (int kk = 0; kk < 4; ++kk) {
          int hd = nf * 16 + lane16;
          int ch = (kk * 4 + lgrp) ^ ((hd ^ (hd >> 3)) & 15);
          bf16x8 vf = *(const bf16x8*)((char*)Vsm + hd * 256 + (ch << 4));
          o[nf] = __builtin_amdgcn_mfma_f32_16x16x32_bf16(
              pa[kk], vf, o[nf], 0, 0, 0);
        }
      }

      __syncthreads();      // all waves done reading Ksm/Vsm before next stage
    }

    // ---- finalize: O / l -> Y (b,t,D) bf16
#pragma unroll
    for (int r = 0; r < 4; ++r) {
      float inv = 1.0f / l_r[r];
      int row = q0 + w * 16 + lgrp * 4 + r;
#pragma unroll
      for (int nf = 0; nf < 8; ++nf) {
        int hd = nf * 16 + lane16;
        Y[(size_t)(b * TT + row) * DM + h * HDD + hd] = (bf16)(o[nf][r] * inv);
      }
    }
  }
}

// ---------------------------------------------------------------- launch
extern "C" void kernel_launch(void* const* d_in, const int* in_sizes, int n_in,
                              void* d_out, int out_size, void* d_ws, size_t ws_size,
                              hipStream_t stream) {
  const float* x = (const float*)d_in[0];
  const float* Wqkv = (const float*)d_in[2];
  const float* bqkv = (const float*)d_in[3];
  const float* Wproj = (const float*)d_in[4];
  const float* bproj = (const float*)d_in[5];
  float* out = (float*)d_out;

  char* ws = (char*)d_ws;
  bf16* xb = (bf16*)ws;                 ws += (size_t)MM * DM * 2;
  bf16* Wqkvt = (bf16*)ws;              ws += (size_t)NQKV * DM * 2;
  bf16* Wprojt = (bf16*)ws;             ws += (size_t)DM * DM * 2;
  bf16* kb = (bf16*)ws;                 ws += (size_t)MM * DM * 2;
  bf16* vb = (bf16*)ws;                 ws += (size_t)MM * DM * 2;
  float* cosT = (float*)ws;             ws += (size_t)TT * 64 * 4;
  float* sinT = (float*)ws;             ws += (size_t)TT * 64 * 4;
  bf16* qb = (bf16*)d_out;              // q lives in d_out (overwritten by proj)
  bf16* yb = xb;                        // xb dead after QKV GEMM

  rope_table_k<<<dim3(512), dim3(256), 0, stream>>>(cosT, sinT);
  convert_x_k<<<dim3(4096), dim3(256), 0, stream>>>(x, xb);
  transpose_w_k<<<dim3(96, 32), dim3(256), 0, stream>>>(Wqkv, Wqkvt, DM, NQKV);
  transpose_w_k<<<dim3(32, 32), dim3(256), 0, stream>>>(Wproj, Wprojt, DM, DM);

  gemm8_qkv_k<<<dim3(16, 32), dim3(512), 0, stream>>>(
      xb, Wqkvt, bqkv, qb, kb, vb, MM, NQKV, DM);

  rope_apply_k<true><<<dim3(4096), dim3(256), 0, stream>>>(qb, cosT, sinT);
  rope_apply_k<false><<<dim3(4096), dim3(256), 0, stream>>>(kb, cosT, sinT);

  attn_k<<<dim3(8, 32), dim3(512), 0, stream>>>(qb, kb, vb, yb);

  gemm4_proj_k<<<dim3(16, 16), dim3(512), 0, stream>>>(
      yb, Wprojt, bproj, out, MM, DM, DM);
}

// Round 13
// 283.693 us; speedup vs baseline: 1.4700x; 1.4700x over previous
//
#include <hip/hip_runtime.h>
#include <hip/hip_bf16.h>
#include <stdint.h>
#include <stddef.h>

typedef __bf16 bf16;
typedef __attribute__((ext_vector_type(8))) __bf16 bf16x8;
typedef __attribute__((ext_vector_type(4))) __bf16 bf16x4;
typedef __attribute__((ext_vector_type(4))) float f32x4;

#define DM 2048      // model dim
#define NH 16        // heads
#define HDD 128      // head dim
#define BB 2         // batch
#define TT 2048      // seq len
#define MM (BB*TT)   // 4096 rows
#define NQKV (3*DM)  // 6144

#define L2E 1.4426950408889634f
#define ATT_SCALE 0.08838834764831845f   // 1/sqrt(128), folded into Q at RoPE
#define NEG_INF (-__builtin_inff())

static_assert(sizeof(bf16x8) == 16, "bf16x8 must be 16B");

#define SB0() __builtin_amdgcn_sched_barrier(0)
#define WAITV0() { asm volatile("s_waitcnt vmcnt(0)" ::: "memory"); SB0(); }
#define WAITL0() { asm volatile("s_waitcnt lgkmcnt(0)" ::: "memory"); SB0(); }
#define BARRIER8() { SB0(); __builtin_amdgcn_s_barrier(); SB0(); }

// ---------------------------------------------------------------- helpers
static __device__ __forceinline__ void gload_lds16(const void* g, void* l) {
  __builtin_amdgcn_global_load_lds(
      (__attribute__((address_space(1))) void*)g,
      (__attribute__((address_space(3))) void*)l, 16, 0, 0);
}

// ---------------------------------------------------------------- pre-pass
__global__ __launch_bounds__(256) void rope_table_k(float* __restrict__ cT,
                                                    float* __restrict__ sT) {
  int id = blockIdx.x * 256 + threadIdx.x;          // < 2048*64
  int t = id >> 6, i = id & 63;
  float freq = powf(10000.0f, -(float)i * (1.0f / 64.0f));
  float theta = (float)t * freq;
  float s, c;
  __sincosf(theta, &s, &c);
  cT[id] = c;
  sT[id] = s;
}

__global__ __launch_bounds__(256) void convert_x_k(const float* __restrict__ x,
                                                   bf16* __restrict__ xb) {
  size_t id = (size_t)blockIdx.x * 256 + threadIdx.x;
  size_t o = id * 8;
  float4 a = *(const float4*)(x + o);
  float4 b = *(const float4*)(x + o + 4);
  bf16x8 r;
  r[0] = (bf16)a.x; r[1] = (bf16)a.y; r[2] = (bf16)a.z; r[3] = (bf16)a.w;
  r[4] = (bf16)b.x; r[5] = (bf16)b.y; r[6] = (bf16)b.z; r[7] = (bf16)b.w;
  *(bf16x8*)(xb + o) = r;
}

// W (K x N) f32 -> Wt (N x K) bf16, 64x64 tiles
__global__ __launch_bounds__(256) void transpose_w_k(const float* __restrict__ W,
                                                     bf16* __restrict__ Wt,
                                                     int K, int N) {
  __shared__ float tile[64][65];
  int n0 = blockIdx.x * 64, k0 = blockIdx.y * 64;
  int t = threadIdx.x;
#pragma unroll
  for (int i = 0; i < 16; ++i) {
    int idx = t + i * 256;
    int r = idx >> 6, c = idx & 63;
    tile[r][c] = W[(size_t)(k0 + r) * N + n0 + c];
  }
  __syncthreads();
#pragma unroll
  for (int i = 0; i < 16; ++i) {
    int idx = t + i * 256;
    int r = idx >> 6, c = idx & 63;
    Wt[(size_t)(n0 + r) * K + k0 + c] = (bf16)tile[c][r];
  }
}

// in-place RoPE on (b,h,t,hd) bf16 buffer; SC folds ATT_SCALE (for Q)
template <bool SC>
__global__ __launch_bounds__(256) void rope_apply_k(bf16* __restrict__ buf,
                                                    const float* __restrict__ cT,
                                                    const float* __restrict__ sT) {
  int id = blockIdx.x * 256 + threadIdx.x;   // < 32*2048*16
  int i4 = id & 15;
  int t = (id >> 4) & 2047;
  int bh = id >> 15;
  int idx0 = i4 * 4;
  size_t base = ((size_t)bh * TT + t) * HDD;
  bf16x4 x1 = *(const bf16x4*)(buf + base + idx0);
  bf16x4 x2 = *(const bf16x4*)(buf + base + 64 + idx0);
  float4 ct = *(const float4*)(cT + t * 64 + idx0);
  float4 st = *(const float4*)(sT + t * 64 + idx0);
  bf16x4 o1, o2;
  float c0, s0, a, b2;
  const float scl = SC ? ATT_SCALE : 1.0f;
#pragma unroll
  for (int j = 0; j < 4; ++j) {
    c0 = (j == 0) ? ct.x : (j == 1) ? ct.y : (j == 2) ? ct.z : ct.w;
    s0 = (j == 0) ? st.x : (j == 1) ? st.y : (j == 2) ? st.z : st.w;
    a = (float)x1[j];
    b2 = (float)x2[j];
    o1[j] = (bf16)((a * c0 - b2 * s0) * scl);
    o2[j] = (bf16)((a * s0 + b2 * c0) * scl);
  }
  *(bf16x4*)(buf + base + idx0) = o1;
  *(bf16x4*)(buf + base + 64 + idx0) = o2;
}

// ---------------------------------------------------------------- GEMM (QKV, 4-phase 256x192)
#define MFMA_Q(MF0, NF0, NCNT)                                             \
  do {                                                                     \
    __builtin_amdgcn_s_setprio(1);                                         \
    _Pragma("unroll") for (int mf = 0; mf < 4; ++mf)                       \
    _Pragma("unroll") for (int nf = 0; nf < (NCNT); ++nf)                  \
    _Pragma("unroll") for (int kk = 0; kk < 2; ++kk)                       \
      acc[(MF0) + mf][(NF0) + nf] = __builtin_amdgcn_mfma_f32_16x16x32_bf16( \
          af[(MF0) + mf][kk], bfr[(NF0) + nf][kk], acc[(MF0) + mf][(NF0) + nf], 0, 0, 0); \
    __builtin_amdgcn_s_setprio(0);                                         \
  } while (0)

__global__ __launch_bounds__(512, 2) void gemm8_qkv_k(
    const bf16* __restrict__ A, const bf16* __restrict__ Bt,
    const float* __restrict__ bias,
    bf16* __restrict__ q_out, bf16* __restrict__ k_out, bf16* __restrict__ v_out,
    int M, int N, int K) {
  __shared__ __align__(16) char Lsm[2][57344];   // [buf][A:32KB | B:24KB]
  const int tid = threadIdx.x;
  const int wid = tid >> 6, l = tid & 63;
  const int lane16 = l & 15, lgrp = l >> 4;
  const int wm = wid >> 2, wn = wid & 3;

  int flat = blockIdx.y * gridDim.x + blockIdx.x;
  {
    const int cpx = (gridDim.x * gridDim.y) >> 3;
    flat = (flat & 7) * cpx + (flat >> 3);
  }
  const int bm = flat % gridDim.x;       // 0..15  (M/256)
  const int bn = flat / gridDim.x;       // 0..31  (N/192)
  const int NT = K >> 6;

  const int schunk = (l & 7) ^ ((l >> 3) & 7);
  const bf16* gA = A + (size_t)(bm * 256 + wid * 8 + (l >> 3)) * K + schunk * 8;
  const bf16* gB = Bt + (size_t)(bn * 192 + wid * 8 + (l >> 3)) * K + schunk * 8;

  auto stage_unit = [&](int mat, int t, int u, int buf) {
    const bf16* g = (mat ? gB : gA) + (size_t)(u * 64) * K + t * 64;
    gload_lds16(g, &Lsm[buf][(mat ? 32768 : 0) + u * 8192 + wid * 1024]);
  };

  f32x4 acc[8][3] = {};

#pragma unroll
  for (int u = 0; u < 4; ++u) stage_unit(0, 0, u, 0);
#pragma unroll
  for (int u = 0; u < 3; ++u) stage_unit(1, 0, u, 0);

  for (int t = 0; t < NT; ++t) {
    const int cur = t & 1;
    const char* As = &Lsm[cur][0];
    const char* Bs = &Lsm[cur][32768];
    bf16x8 af[8][2], bfr[3][2];

    WAITV0();
    BARRIER8();

    // ---- phase 0
#pragma unroll
    for (int mf = 0; mf < 4; ++mf)
#pragma unroll
      for (int kk = 0; kk < 2; ++kk) {
        int row = wm * 128 + mf * 16 + lane16;
        int ch = (kk * 4 + lgrp) ^ (lane16 & 7);
        af[mf][kk] = *(const bf16x8*)(As + row * 128 + ch * 16);
      }
#pragma unroll
    for (int nf = 0; nf < 2; ++nf)
#pragma unroll
      for (int kk = 0; kk < 2; ++kk) {
        int row = wn * 48 + nf * 16 + lane16;
        int ch = (kk * 4 + lgrp) ^ (lane16 & 7);
        bfr[nf][kk] = *(const bf16x8*)(Bs + row * 128 + ch * 16);
      }
    if (t + 1 < NT) {
#pragma unroll
      for (int u = 0; u < 4; ++u) stage_unit(0, t + 1, u, cur ^ 1);
    }
    WAITL0();
    MFMA_Q(0, 0, 2);
    BARRIER8();

    // ---- phase 1
#pragma unroll
    for (int mf = 4; mf < 8; ++mf)
#pragma unroll
      for (int kk = 0; kk < 2; ++kk) {
        int row = wm * 128 + mf * 16 + lane16;
        int ch = (kk * 4 + lgrp) ^ (lane16 & 7);
        af[mf][kk] = *(const bf16x8*)(As + row * 128 + ch * 16);
      }
#pragma unroll
    for (int kk = 0; kk < 2; ++kk) {
      int row = wn * 48 + 32 + lane16;
      int ch = (kk * 4 + lgrp) ^ (lane16 & 7);
      bfr[2][kk] = *(const bf16x8*)(Bs + row * 128 + ch * 16);
    }
    if (t + 1 < NT) {
#pragma unroll
      for (int u = 0; u < 3; ++u) stage_unit(1, t + 1, u, cur ^ 1);
    }
    WAITL0();
    MFMA_Q(0, 2, 1);
    BARRIER8();

    // ---- phase 2
    MFMA_Q(4, 0, 2);
    BARRIER8();

    // ---- phase 3
    MFMA_Q(4, 2, 1);
  }

  // ---- epilogue
#pragma unroll
  for (int nf = 0; nf < 3; ++nf) {
    int colg = bn * 192 + wn * 48 + nf * 16 + lane16;
    int which = colg >> 11;
    bf16* outb = (which == 0) ? q_out : (which == 1 ? k_out : v_out);
    int head = (colg >> 7) & 15, hd = colg & 127;
    float bv = bias[colg];
#pragma unroll
    for (int mf = 0; mf < 8; ++mf)
#pragma unroll
      for (int r = 0; r < 4; ++r) {
        int row = bm * 256 + wm * 128 + mf * 16 + lgrp * 4 + r;
        int bb = row >> 11, tt2 = row & 2047;
        outb[((size_t)(bb * NH + head) * TT + tt2) * HDD + hd] =
            (bf16)(acc[mf][nf][r] + bv);
      }
  }
}

// ---------------------------------------------------------------- GEMM (proj, 4-phase 256x128)
__global__ __launch_bounds__(512, 2) void gemm4_proj_k(
    const bf16* __restrict__ A, const bf16* __restrict__ Bt,
    const float* __restrict__ bias, float* __restrict__ c_out,
    int M, int N, int K) {
  __shared__ __align__(16) char Lsm[2][49152];   // [buf][A:32KB | B:16KB]
  const int tid = threadIdx.x;
  const int wid = tid >> 6, l = tid & 63;
  const int lane16 = l & 15, lgrp = l >> 4;
  const int wm = wid >> 2, wn = wid & 3;

  int flat = blockIdx.y * gridDim.x + blockIdx.x;
  {
    const int cpx = (gridDim.x * gridDim.y) >> 3;
    flat = (flat & 7) * cpx + (flat >> 3);
  }
  const int bm = flat % gridDim.x;       // 0..15 (M/256)
  const int bn = flat / gridDim.x;       // 0..15 (N/128)
  const int NT = K >> 6;

  const int schunk = (l & 7) ^ ((l >> 3) & 7);
  const bf16* gA = A + (size_t)(bm * 256 + wid * 8 + (l >> 3)) * K + schunk * 8;
  const bf16* gB = Bt + (size_t)(bn * 128 + wid * 8 + (l >> 3)) * K + schunk * 8;

  auto stage_unit = [&](int mat, int t, int u, int buf) {
    const bf16* g = (mat ? gB : gA) + (size_t)(u * 64) * K + t * 64;
    gload_lds16(g, &Lsm[buf][(mat ? 32768 : 0) + u * 8192 + wid * 1024]);
  };

  f32x4 acc[8][2] = {};

#pragma unroll
  for (int u = 0; u < 4; ++u) stage_unit(0, 0, u, 0);
#pragma unroll
  for (int u = 0; u < 2; ++u) stage_unit(1, 0, u, 0);

  for (int t = 0; t < NT; ++t) {
    const int cur = t & 1;
    const char* As = &Lsm[cur][0];
    const char* Bs = &Lsm[cur][32768];
    bf16x8 af[8][2], bfr[2][2];

    WAITV0();
    BARRIER8();

    // ---- phase 0
#pragma unroll
    for (int mf = 0; mf < 4; ++mf)
#pragma unroll
      for (int kk = 0; kk < 2; ++kk) {
        int row = wm * 128 + mf * 16 + lane16;
        int ch = (kk * 4 + lgrp) ^ (lane16 & 7);
        af[mf][kk] = *(const bf16x8*)(As + row * 128 + ch * 16);
      }
#pragma unroll
    for (int nf = 0; nf < 2; ++nf)
#pragma unroll
      for (int kk = 0; kk < 2; ++kk) {
        int row = wn * 32 + nf * 16 + lane16;
        int ch = (kk * 4 + lgrp) ^ (lane16 & 7);
        bfr[nf][kk] = *(const bf16x8*)(Bs + row * 128 + ch * 16);
      }
    if (t + 1 < NT) {
#pragma unroll
      for (int u = 0; u < 4; ++u) stage_unit(0, t + 1, u, cur ^ 1);
    }
    WAITL0();
    MFMA_Q(0, 0, 1);
    BARRIER8();

    // ---- phase 1
#pragma unroll
    for (int mf = 4; mf < 8; ++mf)
#pragma unroll
      for (int kk = 0; kk < 2; ++kk) {
        int row = wm * 128 + mf * 16 + lane16;
        int ch = (kk * 4 + lgrp) ^ (lane16 & 7);
        af[mf][kk] = *(const bf16x8*)(As + row * 128 + ch * 16);
      }
    if (t + 1 < NT) {
#pragma unroll
      for (int u = 0; u < 2; ++u) stage_unit(1, t + 1, u, cur ^ 1);
    }
    WAITL0();
    MFMA_Q(0, 1, 1);
    BARRIER8();

    // ---- phase 2
    MFMA_Q(4, 0, 1);
    BARRIER8();

    // ---- phase 3
    MFMA_Q(4, 1, 1);
  }

  // ---- epilogue: bias + f32 row-major store
#pragma unroll
  for (int nf = 0; nf < 2; ++nf) {
    int colg = bn * 128 + wn * 32 + nf * 16 + lane16;
    float bv = bias[colg];
#pragma unroll
    for (int mf = 0; mf < 8; ++mf)
#pragma unroll
      for (int r = 0; r < 4; ++r) {
        int row = bm * 256 + wm * 128 + mf * 16 + lgrp * 4 + r;
        c_out[(size_t)row * N + colg] = acc[mf][nf][r] + bv;
      }
  }
}

// ---------------------------------------------------------------- attention
// R9-proven structure + Q-prescale (mask only on diagonal tile). Softmax is
// the R11 UNCONDITIONAL rescale — R12's defer-max branch caused VGPR spills
// (WRITE_SIZE 18->92MB, dur 121->243us) at the 128-VGPR/2-block occupancy
// point; divergent liveness-extending branches in the softmax are retired.
__global__ __launch_bounds__(512, 2) void attn_k(
    const bf16* __restrict__ Q, const bf16* __restrict__ Kt,
    const bf16* __restrict__ V, bf16* __restrict__ Y) {
  __shared__ __align__(16) bf16 Ksm[128 * 128];   // [key][hd], chunk^=g4(key), 32KB
  __shared__ __align__(16) bf16 Vsm[128 * 128];   // [hd][key], chunk^=g4(hd), 32KB
  __shared__ __align__(16) bf16 Psm[8][16 * 128]; // per-wave P, chunk^=g4(row), 32KB
  const int tid = threadIdx.x, w = tid >> 6, l = tid & 63;
  const int lane16 = l & 15, lgrp = l >> 4;
  const int bh = blockIdx.y;
  const int b = bh >> 4, h = bh & 15;
  const size_t base = (size_t)bh * TT * HDD;

  uint4 vreg[4];
  const int vg = tid >> 4, vh8 = tid & 15;

  auto load_V = [&](int k0) {
#pragma unroll
    for (int kq = 0; kq < 4; ++kq)
      vreg[kq] = *(const uint4*)(V + base + (size_t)(k0 + vg * 4 + kq) * HDD + vh8 * 8);
  };
  auto issue_K = [&](int k0) {
#pragma unroll
    for (int i = 0; i < 4; ++i) {
      int key = w * 16 + i * 4 + (l >> 4);
      int c = (l & 15) ^ ((key ^ (key >> 3)) & 15);
      gload_lds16(Kt + base + (size_t)(k0 + key) * HDD + c * 8,
                  &Ksm[(w * 16 + i * 4) * 128 + (l & 15) * 8]);
    }
  };
  auto write_V = [&]() {
    const unsigned* dw = (const unsigned*)vreg;
    int hd0 = vh8 * 8;
#pragma unroll
    for (int j = 0; j < 8; ++j) {
      int ww = j >> 1;
      unsigned sel = (j & 1) ? 0x07060302u : 0x05040100u;
      uint2 val;
      val.x = __builtin_amdgcn_perm(dw[4 + ww], dw[0 + ww], sel);
      val.y = __builtin_amdgcn_perm(dw[12 + ww], dw[8 + ww], sel);
      int hd = hd0 + j;
      int ch = (vg >> 1) ^ ((hd ^ (hd >> 3)) & 15);
      *(uint2*)((char*)Vsm + hd * 256 + (ch << 4) + ((vg & 1) << 3)) = val;
    }
  };

  for (int pass = 0; pass < 2; ++pass) {
    const int qt = (pass == 0) ? (int)blockIdx.x : 15 - (int)blockIdx.x;
    const int q0 = qt * 128;
    const int nt = qt + 1;

    bf16x8 qa[4];
    {
      int row = q0 + w * 16 + lane16;
#pragma unroll
      for (int kk = 0; kk < 4; ++kk)
        qa[kk] = *(const bf16x8*)(Q + base + (size_t)row * HDD + kk * 32 + lgrp * 8);
    }

    f32x4 o[8] = {};
    float m_r[4], l_r[4];
#pragma unroll
    for (int r = 0; r < 4; ++r) { m_r[r] = NEG_INF; l_r[r] = 0.f; }

    for (int kt = 0; kt < nt; ++kt) {
      const int k0 = kt * 128;
      load_V(k0);           // V loads first (oldest in vmcnt queue)
      issue_K(k0);          // K direct-to-LDS, in flight during V repack
      write_V();            // waits only the 4 V loads; WAR safe (prev barrier)
      __syncthreads();      // drains vmcnt+lgkmcnt: K & V staged for all waves

      // ---- S = Q K^T  (logits pre-scaled via Q)
      f32x4 s[8] = {};
#pragma unroll
      for (int kk = 0; kk < 4; ++kk) {
#pragma unroll
        for (int nf = 0; nf < 8; ++nf) {
          int key = nf * 16 + lane16;
          int ch = (kk * 4 + lgrp) ^ ((key ^ (key >> 3)) & 15);
          bf16x8 kf = *(const bf16x8*)((char*)Ksm + key * 256 + (ch << 4));
          s[nf] = __builtin_amdgcn_mfma_f32_16x16x32_bf16(
              qa[kk], kf, s[nf], 0, 0, 0);
        }
      }

      // ---- causal mask (diagonal tile only; wave-uniform branch)
      if (k0 + 127 > q0 + w * 16) {
        const int rowbase = q0 + w * 16 + lgrp * 4;
#pragma unroll
        for (int nf = 0; nf < 8; ++nf) {
          int col = k0 + nf * 16 + lane16;
#pragma unroll
          for (int r = 0; r < 4; ++r)
            if (col > rowbase + r) s[nf][r] = -3.0e38f;
        }
      }

      // ---- online softmax (unconditional rescale — straight-line)
#pragma unroll
      for (int r = 0; r < 4; ++r) {
        float tm = fmaxf(fmaxf(fmaxf(s[0][r], s[1][r]), fmaxf(s[2][r], s[3][r])),
                         fmaxf(fmaxf(s[4][r], s[5][r]), fmaxf(s[6][r], s[7][r])));
        tm = fmaxf(tm, __shfl_xor(tm, 1));
        tm = fmaxf(tm, __shfl_xor(tm, 2));
        tm = fmaxf(tm, __shfl_xor(tm, 4));
        tm = fmaxf(tm, __shfl_xor(tm, 8));
        float mo = m_r[r];
        float mn = fmaxf(mo, tm);
        float alpha = exp2f((mo - mn) * L2E);
        m_r[r] = mn;
        float rs = 0.f;
#pragma unroll
        for (int nf = 0; nf < 8; ++nf) {
          float p = exp2f((s[nf][r] - mn) * L2E);
          s[nf][r] = p;
          rs += p;
        }
        rs += __shfl_xor(rs, 1);
        rs += __shfl_xor(rs, 2);
        rs += __shfl_xor(rs, 4);
        rs += __shfl_xor(rs, 8);
        l_r[r] = l_r[r] * alpha + rs;
#pragma unroll
        for (int nf = 0; nf < 8; ++nf) o[nf][r] *= alpha;
      }

      // ---- P -> LDS (per-wave region, same-wave readback; no barrier)
#pragma unroll
      for (int nf = 0; nf < 8; ++nf)
#pragma unroll
        for (int r = 0; r < 4; ++r) {
          int rl = lgrp * 4 + r;
          int ch = (2 * nf + (lane16 >> 3)) ^ ((rl ^ (rl >> 3)) & 15);
          int byte = rl * 256 + (ch << 4) + ((lane16 & 7) << 1);
          *(bf16*)((char*)&Psm[w][0] + byte) = (bf16)s[nf][r];
        }
      bf16x8 pa[4];
#pragma unroll
      for (int kk = 0; kk < 4; ++kk) {
        int ch = (kk * 4 + lgrp) ^ ((lane16 ^ (lane16 >> 3)) & 15);
        pa[kk] = *(const bf16x8*)((char*)&Psm[w][0] + lane16 * 256 + (ch << 4));
      }

      // ---- O += P V
#pragma unroll
      for (int nf = 0; nf < 8; ++nf) {
#pragma unroll
        for (int kk = 0; kk < 4; ++kk) {
          int hd = nf * 16 + lane16;
          int ch = (kk * 4 + lgrp) ^ ((hd ^ (hd >> 3)) & 15);
          bf16x8 vf = *(const bf16x8*)((char*)Vsm + hd * 256 + (ch << 4));
          o[nf] = __builtin_amdgcn_mfma_f32_16x16x32_bf16(
              pa[kk], vf, o[nf], 0, 0, 0);
        }
      }

      __syncthreads();      // all waves done reading Ksm/Vsm before next stage
    }

    // ---- finalize: O / l -> Y (b,t,D) bf16
#pragma unroll
    for (int r = 0; r < 4; ++r) {
      float inv = 1.0f / l_r[r];
      int row = q0 + w * 16 + lgrp * 4 + r;
#pragma unroll
      for (int nf = 0; nf < 8; ++nf) {
        int hd = nf * 16 + lane16;
        Y[(size_t)(b * TT + row) * DM + h * HDD + hd] = (bf16)(o[nf][r] * inv);
      }
    }
  }
}

// ---------------------------------------------------------------- launch
extern "C" void kernel_launch(void* const* d_in, const int* in_sizes, int n_in,
                              void* d_out, int out_size, void* d_ws, size_t ws_size,
                              hipStream_t stream) {
  const float* x = (const float*)d_in[0];
  const float* Wqkv = (const float*)d_in[2];
  const float* bqkv = (const float*)d_in[3];
  const float* Wproj = (const float*)d_in[4];
  const float* bproj = (const float*)d_in[5];
  float* out = (float*)d_out;

  char* ws = (char*)d_ws;
  bf16* xb = (bf16*)ws;                 ws += (size_t)MM * DM * 2;
  bf16* Wqkvt = (bf16*)ws;              ws += (size_t)NQKV * DM * 2;
  bf16* Wprojt = (bf16*)ws;             ws += (size_t)DM * DM * 2;
  bf16* kb = (bf16*)ws;                 ws += (size_t)MM * DM * 2;
  bf16* vb = (bf16*)ws;                 ws += (size_t)MM * DM * 2;
  float* cosT = (float*)ws;             ws += (size_t)TT * 64 * 4;
  float* sinT = (float*)ws;             ws += (size_t)TT * 64 * 4;
  bf16* qb = (bf16*)d_out;              // q lives in d_out (overwritten by proj)
  bf16* yb = xb;                        // xb dead after QKV GEMM

  rope_table_k<<<dim3(512), dim3(256), 0, stream>>>(cosT, sinT);
  convert_x_k<<<dim3(4096), dim3(256), 0, stream>>>(x, xb);
  transpose_w_k<<<dim3(96, 32), dim3(256), 0, stream>>>(Wqkv, Wqkvt, DM, NQKV);
  transpose_w_k<<<dim3(32, 32), dim3(256), 0, stream>>>(Wproj, Wprojt, DM, DM);

  gemm8_qkv_k<<<dim3(16, 32), dim3(512), 0, stream>>>(
      xb, Wqkvt, bqkv, qb, kb, vb, MM, NQKV, DM);

  rope_apply_k<true><<<dim3(4096), dim3(256), 0, stream>>>(qb, cosT, sinT);
  rope_apply_k<false><<<dim3(4096), dim3(256), 0, stream>>>(kb, cosT, sinT);

  attn_k<<<dim3(8, 32), dim3(512), 0, stream>>>(qb, kb, vb, yb);

  gemm4_proj_k<<<dim3(16, 16), dim3(512), 0, stream>>>(
      yb, Wprojt, bproj, out, MM, DM, DM);
}